// Round 9
// baseline (379.265 us; speedup 1.0000x reference)
//
#include <hip/hip_runtime.h>

#define N_NODESC 50000
#define N_EDGESC 600000
#define DDIM 128
#define NCLASS 40
#define BN_EPS 1e-5f
#define STAT_BLOCKS 196     // ceil(50000/256)
#define GATHER_BLOCKS 1024  // x 512 threads (8 waves)
#define L1_BLOCKS 782       // 3128 tiles of 16 rows
#define ACT_BLOCKS 3125     // 50000*16/256
#define W1P_BLOCKS 64       // 16384/256
#define SORT_ROWS 128
#define SORT_CAP 2560
#define SORT_BLOCKS 391

typedef short bhalf8 __attribute__((ext_vector_type(8)));
typedef float f32x4 __attribute__((ext_vector_type(4)));

union ABfrag { bhalf8 v; unsigned short u[8]; uint4 q; };

__device__ inline float bflo(unsigned d) { return __builtin_bit_cast(float, d << 16); }
__device__ inline float bfhi(unsigned d) { return __builtin_bit_cast(float, d & 0xffff0000u); }
__device__ inline unsigned short f2bf(float f) {
    unsigned u = __builtin_bit_cast(unsigned, f);
    u += 0x7fffu + ((u >> 16) & 1u);        // RNE
    return (unsigned short)(u >> 16);
}

// ---------------- degree ----------------
__global__ __launch_bounds__(256) void deg_kernel(const int* __restrict__ dst, int* __restrict__ deg) {
    int e = blockIdx.x * 256 + threadIdx.x;
    if (e < N_EDGESC) atomicAdd(&deg[dst[e]], 1);
}

// ---------------- hierarchical exclusive scan: deg -> rowptr (+ nrm fused) ----------------
__global__ __launch_bounds__(256) void scan1_kernel(const int* __restrict__ deg,
                                                    int* __restrict__ rowptr,
                                                    int* __restrict__ blocksums) {
    __shared__ int sh[256];
    int t = threadIdx.x;
    int i = blockIdx.x * 256 + t;
    int v = (i < N_NODESC) ? deg[i] : 0;
    sh[t] = v;
    __syncthreads();
    #pragma unroll
    for (int off = 1; off < 256; off <<= 1) {
        int tv = (t >= off) ? sh[t - off] : 0;
        __syncthreads();
        sh[t] += tv;
        __syncthreads();
    }
    if (i < N_NODESC) rowptr[i] = sh[t] - v;
    if (t == 255) blocksums[blockIdx.x] = sh[255];
}

__global__ void scan2_kernel(const int* __restrict__ blocksums, int* __restrict__ blockoff) {
    __shared__ int sh[256];
    int t = threadIdx.x;
    int v = (t < STAT_BLOCKS) ? blocksums[t] : 0;
    sh[t] = v;
    __syncthreads();
    #pragma unroll
    for (int off = 1; off < 256; off <<= 1) {
        int tv = (t >= off) ? sh[t - off] : 0;
        __syncthreads();
        sh[t] += tv;
        __syncthreads();
    }
    blockoff[t] = sh[t] - v;
}

__global__ __launch_bounds__(256) void scan3_kernel(int* __restrict__ rowptr,
                                                    const int* __restrict__ blockoff,
                                                    const int* __restrict__ deg,
                                                    int* __restrict__ cursor,
                                                    float* __restrict__ nrm) {
    int i = blockIdx.x * 256 + threadIdx.x;
    if (i < N_NODESC) {
        int r = rowptr[i] + blockoff[blockIdx.x];
        rowptr[i] = r;
        cursor[i] = r;
        nrm[i] = rsqrtf(fmaxf((float)deg[i], 1.0f));
    }
    if (blockIdx.x == 0 && threadIdx.x == 0) rowptr[N_NODESC] = N_EDGESC;
}

// ---------------- CSR fill + deterministic per-row LDS sort ----------------
__global__ __launch_bounds__(256) void fill_kernel(const int* __restrict__ src,
                                                   const int* __restrict__ dst,
                                                   int* __restrict__ cursor,
                                                   int* __restrict__ csr) {
    int e = blockIdx.x * 256 + threadIdx.x;
    if (e < N_EDGESC) {
        int d = dst[e];
        int p = atomicAdd(&cursor[d], 1);
        csr[p] = src[e];
    }
}

__global__ __launch_bounds__(128) void sortrows_kernel(const int* __restrict__ rowptr,
                                                       int* __restrict__ csr) {
    __shared__ int buf[SORT_CAP];
    int r0 = blockIdx.x * SORT_ROWS;
    int r1 = r0 + SORT_ROWS; if (r1 > N_NODESC) r1 = N_NODESC;
    int base = rowptr[r0];
    int end  = rowptr[r1];
    int cnt  = end - base;
    if (cnt <= SORT_CAP) {
        for (int j = threadIdx.x; j < cnt; j += 128) buf[j] = csr[base + j];
        __syncthreads();
        int i = r0 + threadIdx.x;
        if (i < r1) {
            int b = rowptr[i] - base, e = rowptr[i + 1] - base;
            for (int j = b + 1; j < e; j++) {
                int v = buf[j];
                int k = j - 1;
                while (k >= b && buf[k] > v) { buf[k + 1] = buf[k]; k--; }
                buf[k + 1] = v;
            }
        }
        __syncthreads();
        for (int j = threadIdx.x; j < cnt; j += 128) csr[base + j] = buf[j];
    } else {
        int i = r0 + threadIdx.x;
        if (i < r1) {
            int b = rowptr[i], e = rowptr[i + 1];
            for (int j = b + 1; j < e; j++) {
                int v = csr[j];
                int k = j - 1;
                while (k >= b && csr[k] > v) { csr[k + 1] = csr[k]; k--; }
                csr[k + 1] = v;
            }
        }
    }
}

// ---------------- layer-0 act (fp32 in): Z = bf16(nrm*h); extra blocks do W1 -> bf16 [n][k] ----------------
__global__ __launch_bounds__(256) void act0_kernel(const float* __restrict__ in,
                                                   const float* __restrict__ nrm,
                                                   unsigned short* __restrict__ Z,
                                                   const float* __restrict__ W1,
                                                   unsigned short* __restrict__ W1T) {
    if (blockIdx.x >= ACT_BLOCKS) {
        int idx = (blockIdx.x - ACT_BLOCKS) * 256 + threadIdx.x;
        if (idx < DDIM * DDIM) {
            int k = idx >> 7, n = idx & 127;
            W1T[n * DDIM + k] = f2bf(W1[idx]);
        }
        return;
    }
    int t = blockIdx.x * 256 + threadIdx.x;
    int i = t >> 4;
    int c = (t & 15) * 8;
    if (i >= N_NODESC) return;
    const float* rp = in + (size_t)i * DDIM + c;
    float4 v0 = *reinterpret_cast<const float4*>(rp);
    float4 v1 = *reinterpret_cast<const float4*>(rp + 4);
    float ni = nrm[i];
    float a[8] = {v0.x*ni, v0.y*ni, v0.z*ni, v0.w*ni, v1.x*ni, v1.y*ni, v1.z*ni, v1.w*ni};
    uint4 p;
    p.x = (unsigned)f2bf(a[0]) | ((unsigned)f2bf(a[1]) << 16);
    p.y = (unsigned)f2bf(a[2]) | ((unsigned)f2bf(a[3]) << 16);
    p.z = (unsigned)f2bf(a[4]) | ((unsigned)f2bf(a[5]) << 16);
    p.w = (unsigned)f2bf(a[6]) | ((unsigned)f2bf(a[7]) << 16);
    *reinterpret_cast<uint4*>(Z + (size_t)i * DDIM + c) = p;
}

// ---------------- activation prepass (bf16 in): Z = bf16( (NRM?nrm:1) * relu(x*sc+sh) ) ----------------
template <bool NRM>
__global__ __launch_bounds__(256) void act_bf16_kernel(const unsigned short* __restrict__ in,
                                                       const float* __restrict__ nrm,
                                                       const float* __restrict__ mu,
                                                       const float* __restrict__ rstd,
                                                       const float* __restrict__ gamma,
                                                       const float* __restrict__ beta,
                                                       unsigned short* __restrict__ Z) {
    int t = blockIdx.x * 256 + threadIdx.x;
    int i = t >> 4;
    int c = (t & 15) * 8;
    if (i >= N_NODESC) return;
    uint4 d = *reinterpret_cast<const uint4*>(in + (size_t)i * DDIM + c);
    float a[8] = {bflo(d.x), bfhi(d.x), bflo(d.y), bfhi(d.y),
                  bflo(d.z), bfhi(d.z), bflo(d.w), bfhi(d.w)};
    float4 m0 = *reinterpret_cast<const float4*>(mu + c);
    float4 m1 = *reinterpret_cast<const float4*>(mu + c + 4);
    float4 r0 = *reinterpret_cast<const float4*>(rstd + c);
    float4 r1 = *reinterpret_cast<const float4*>(rstd + c + 4);
    float4 g0 = *reinterpret_cast<const float4*>(gamma + c);
    float4 g1 = *reinterpret_cast<const float4*>(gamma + c + 4);
    float4 b0 = *reinterpret_cast<const float4*>(beta + c);
    float4 b1 = *reinterpret_cast<const float4*>(beta + c + 4);
    float sc[8] = {r0.x*g0.x, r0.y*g0.y, r0.z*g0.z, r0.w*g0.w,
                   r1.x*g1.x, r1.y*g1.y, r1.z*g1.z, r1.w*g1.w};
    float sh[8] = {b0.x-m0.x*sc[0], b0.y-m0.y*sc[1], b0.z-m0.z*sc[2], b0.w-m0.w*sc[3],
                   b1.x-m1.x*sc[4], b1.y-m1.y*sc[5], b1.z-m1.z*sc[6], b1.w-m1.w*sc[7]};
    #pragma unroll
    for (int k = 0; k < 8; k++) a[k] = fmaxf(a[k] * sc[k] + sh[k], 0.f);
    if (NRM) {
        float ni = nrm[i];
        #pragma unroll
        for (int k = 0; k < 8; k++) a[k] *= ni;
    }
    uint4 p;
    p.x = (unsigned)f2bf(a[0]) | ((unsigned)f2bf(a[1]) << 16);
    p.y = (unsigned)f2bf(a[2]) | ((unsigned)f2bf(a[3]) << 16);
    p.z = (unsigned)f2bf(a[4]) | ((unsigned)f2bf(a[5]) << 16);
    p.w = (unsigned)f2bf(a[6]) | ((unsigned)f2bf(a[7]) << 16);
    *reinterpret_cast<uint4*>(Z + (size_t)i * DDIM + c) = p;
}

// ---------------- gather: Xb[i] = bf16(nrm[i] * sum Z[s]); fused BN stats (pre-round fp32) ----------------
// 512 threads = 8 waves; wave: 4 edge slots x 16 col-lanes (8 cols each); 2-deep row prefetch
__global__ __launch_bounds__(512) void gather_kernel(const unsigned short* __restrict__ Z,
                                                     const float* __restrict__ nrm,
                                                     const int* __restrict__ rowptr,
                                                     const int* __restrict__ csr,
                                                     unsigned short* __restrict__ Xb,
                                                     float* __restrict__ partials) {
    __shared__ float red[8][256];
    int lane = threadIdx.x & 63;
    int wave = threadIdx.x >> 6;   // 0..7
    int slot = lane >> 4;          // 0..3
    int c    = lane & 15;          // col group: cols [8c, 8c+8)
    float ssum[8] = {0.f,0.f,0.f,0.f,0.f,0.f,0.f,0.f};
    float sqr[8]  = {0.f,0.f,0.f,0.f,0.f,0.f,0.f,0.f};
    for (int i = blockIdx.x * 8 + wave; i < N_NODESC; i += GATHER_BLOCKS * 8) {
        int b = rowptr[i], e = rowptr[i + 1];
        float a[8] = {0.f,0.f,0.f,0.f,0.f,0.f,0.f,0.f};
        int j = b + slot;
        bool v0 = j < e, v1 = j + 4 < e, v2 = j + 8 < e;
        uint4 r0 = make_uint4(0,0,0,0), r1 = r0, r2 = r0;
        if (v0) r0 = reinterpret_cast<const uint4*>(Z + (size_t)csr[j]     * DDIM)[c];
        if (v1) r1 = reinterpret_cast<const uint4*>(Z + (size_t)csr[j + 4] * DDIM)[c];
        if (v2) r2 = reinterpret_cast<const uint4*>(Z + (size_t)csr[j + 8] * DDIM)[c];
        int jn = j + 12;
        while (v0) {
            a[0] += bflo(r0.x); a[1] += bfhi(r0.x);
            a[2] += bflo(r0.y); a[3] += bfhi(r0.y);
            a[4] += bflo(r0.z); a[5] += bfhi(r0.z);
            a[6] += bflo(r0.w); a[7] += bfhi(r0.w);
            r0 = r1; v0 = v1;
            r1 = r2; v1 = v2;
            v2 = jn < e;
            if (v2) r2 = reinterpret_cast<const uint4*>(Z + (size_t)csr[jn] * DDIM)[c];
            jn += 4;
        }
        #pragma unroll
        for (int t = 0; t < 8; t++) {
            a[t] += __shfl_xor(a[t], 16);
            a[t] += __shfl_xor(a[t], 32);
        }
        if (slot == 0) {
            float ni = nrm[i];
            #pragma unroll
            for (int t = 0; t < 8; t++) {
                a[t] *= ni;
                ssum[t] += a[t];
                sqr[t]  += a[t] * a[t];
            }
            uint4 p;
            p.x = (unsigned)f2bf(a[0]) | ((unsigned)f2bf(a[1]) << 16);
            p.y = (unsigned)f2bf(a[2]) | ((unsigned)f2bf(a[3]) << 16);
            p.z = (unsigned)f2bf(a[4]) | ((unsigned)f2bf(a[5]) << 16);
            p.w = (unsigned)f2bf(a[6]) | ((unsigned)f2bf(a[7]) << 16);
            reinterpret_cast<uint4*>(Xb + (size_t)i * DDIM)[c] = p;
        }
    }
    if (slot == 0) {
        #pragma unroll
        for (int t = 0; t < 8; t++) {
            red[wave][c * 8 + t]       = ssum[t];
            red[wave][128 + c * 8 + t] = sqr[t];
        }
    }
    __syncthreads();
    int tid = threadIdx.x;
    if (tid < 256) {
        float s = 0.f;
        #pragma unroll
        for (int w = 0; w < 8; w++) s += red[w][tid];
        partials[(size_t)blockIdx.x * 256 + tid] = s;
    }
}

// ---------------- fused deterministic stats reduce: 32 blocks; last block finishes in fp64 ----------------
// FOLD=true additionally folds BN2 into W2/b2 in the last block.
template <bool FOLD>
__global__ __launch_bounds__(256) void redfuse_kernel(const float* __restrict__ partials, int nrows,
                                                      float* __restrict__ p2,
                                                      unsigned int* __restrict__ counter,
                                                      float* __restrict__ mu, float* __restrict__ rstd,
                                                      const float* __restrict__ W2, const float* __restrict__ b2,
                                                      const float* __restrict__ g2, const float* __restrict__ be2,
                                                      float* __restrict__ W2f, float* __restrict__ b2f) {
    int col = threadIdx.x;
    float s = 0.f;
    for (int r = blockIdx.x; r < nrows; r += 32) s += partials[(size_t)r * 256 + col];
    p2[(size_t)blockIdx.x * 256 + col] = s;
    __threadfence();
    __shared__ unsigned int lastFlag;
    if (col == 0) lastFlag = (atomicAdd(counter, 1u) == 31u) ? 1u : 0u;
    __syncthreads();
    if (!lastFlag) return;
    if (col == 0) *counter = 0u;          // self-reset for the next use
    __threadfence();                      // acquire: see all p2 writes
    int c = col & 127;
    int isq = col >> 7;
    double acc = 0.0;
    for (int r = 0; r < 32; r++) acc += (double)p2[(size_t)r * 256 + isq * 128 + c];
    __shared__ double shd[256];
    __shared__ float sfold[128], tfold[128];
    __shared__ float f4[4][64];
    shd[col] = acc;
    __syncthreads();
    if (col < 128) {
        double m = shd[col] / (double)N_NODESC;
        double v = shd[col + 128] / (double)N_NODESC - m * m;
        if (v < 0.0) v = 0.0;
        float rs = rsqrtf((float)v + BN_EPS);
        mu[col]   = (float)m;
        rstd[col] = rs;
        if (FOLD) {
            float sc = rs * g2[col];
            sfold[col] = sc;
            tfold[col] = be2[col] - (float)m * sc;
        }
    }
    if (FOLD) {
        __syncthreads();
        for (int idx = col; idx < DDIM * NCLASS; idx += 256) {
            W2f[idx] = W2[idx] * sfold[idx / NCLASS];
        }
        int c2 = col & 63, sl2 = col >> 6;
        float accf = 0.f;
        if (c2 < NCLASS) {
            for (int k = sl2 * 32; k < sl2 * 32 + 32; k++) accf += tfold[k] * W2[k * NCLASS + c2];
        }
        f4[sl2][c2] = accf;
        __syncthreads();
        if (col < NCLASS) {
            b2f[col] = b2[col] + f4[0][col] + f4[1][col] + f4[2][col] + f4[3][col];
        }
    }
}

// ---------------- GEMM1 (MFMA): X = Z4 @ W1 + b1 (Z4 pre-activated bf16), fused BN2 stats ----------------
__global__ __launch_bounds__(256) void linear1_mfma(const unsigned short* __restrict__ Z4,
                                                    const unsigned short* __restrict__ W1T,
                                                    const float* __restrict__ b1,
                                                    float* __restrict__ X,
                                                    float* __restrict__ partials) {
    __shared__ uint4 wlds[2048];               // 32 KB: W1T bf16 [n][k], XOR-swizzled
    __shared__ float bias[DDIM];
    __shared__ float red[4][256];
    int tid = threadIdx.x;
    for (int i = tid; i < 2048; i += 256) {
        uint4 v = reinterpret_cast<const uint4*>(W1T)[i];
        int o = i << 4;
        int n = o >> 8;
        int sw = (o & 255) ^ ((n & 7) << 4);
        wlds[(n << 4) | (sw >> 4)] = v;
    }
    if (tid < DDIM) bias[tid] = b1[tid];
    __syncthreads();
    int wave = tid >> 6, lane = tid & 63;
    int l15 = lane & 15, l4 = lane >> 4;
    int tile = blockIdx.x * 4 + wave;          // < 3128
    int row0 = tile * 16;
    int arow = row0 + l15; if (arow >= N_NODESC) arow = N_NODESC - 1;
    const uint4* aptr = reinterpret_cast<const uint4*>(Z4 + (size_t)arow * DDIM);
    f32x4 acc[8];
    #pragma unroll
    for (int cf = 0; cf < 8; cf++) acc[cf] = (f32x4){0.f, 0.f, 0.f, 0.f};
    #pragma unroll
    for (int ks = 0; ks < 4; ks++) {
        ABfrag a;
        a.q = aptr[ks * 4 + l4];
        int koff = ks * 64 + l4 * 16;
        #pragma unroll
        for (int cf = 0; cf < 8; cf++) {
            int n = cf * 16 + l15;
            ABfrag b;
            b.q = wlds[(n << 4) | ((koff ^ ((n & 7) << 4)) >> 4)];
            acc[cf] = __builtin_amdgcn_mfma_f32_16x16x32_bf16(a.v, b.v, acc[cf], 0, 0, 0);
        }
    }
    float cs[8], cq[8];
    #pragma unroll
    for (int cf = 0; cf < 8; cf++) {
        int col = cf * 16 + l15;
        float bb = bias[col];
        float sl_ = 0.f, ql_ = 0.f;
        #pragma unroll
        for (int r = 0; r < 4; r++) {
            int row = row0 + l4 * 4 + r;
            float x = acc[cf][r] + bb;
            if (row < N_NODESC) {
                X[(size_t)row * DDIM + col] = x;
                sl_ += x;
                ql_ += x * x;
            }
        }
        sl_ += __shfl_xor(sl_, 16); sl_ += __shfl_xor(sl_, 32);
        ql_ += __shfl_xor(ql_, 16); ql_ += __shfl_xor(ql_, 32);
        cs[cf] = sl_; cq[cf] = ql_;
    }
    if (l4 == 0) {
        #pragma unroll
        for (int cf = 0; cf < 8; cf++) {
            red[wave][cf * 16 + l15]       = cs[cf];
            red[wave][128 + cf * 16 + l15] = cq[cf];
        }
    }
    __syncthreads();
    if (tid < 256) {
        partials[(size_t)blockIdx.x * 256 + tid] = red[0][tid] + red[1][tid] + red[2][tid] + red[3][tid];
    }
}

// ---------------- GEMM2: out = X @ W2f + b2f ----------------
#define L2_TILE 64
__global__ __launch_bounds__(256) void linear2_kernel(const float* __restrict__ X,
                                                      const float* __restrict__ W2f,
                                                      const float* __restrict__ b2f,
                                                      float* __restrict__ out) {
    __shared__ float Ws[DDIM][NCLASS];  // 20 KB
    for (int idx = threadIdx.x; idx < DDIM * NCLASS; idx += 256) {
        (&Ws[0][0])[idx] = W2f[idx];
    }
    __syncthreads();
    int cg = threadIdx.x & 7;
    int rp = threadIdx.x >> 3;
    int c0 = cg * 5;
    for (int base = blockIdx.x * L2_TILE; base < N_NODESC; base += gridDim.x * L2_TILE) {
        int row0 = base + rp * 2;
        int row1 = row0 + 1;
        int r0c = row0 < N_NODESC ? row0 : (N_NODESC - 1);
        int r1c = row1 < N_NODESC ? row1 : (N_NODESC - 1);
        const float* r0p = X + (size_t)r0c * DDIM;
        const float* r1p = X + (size_t)r1c * DDIM;
        float a0[5] = {0.f, 0.f, 0.f, 0.f, 0.f};
        float a1[5] = {0.f, 0.f, 0.f, 0.f, 0.f};
        #pragma unroll 4
        for (int k4 = 0; k4 < DDIM; k4 += 4) {
            float4 x0 = *reinterpret_cast<const float4*>(r0p + k4);
            float4 x1 = *reinterpret_cast<const float4*>(r1p + k4);
            #pragma unroll
            for (int j = 0; j < 5; j++) {
                float w0 = Ws[k4 + 0][c0 + j];
                float w1 = Ws[k4 + 1][c0 + j];
                float w2 = Ws[k4 + 2][c0 + j];
                float w3 = Ws[k4 + 3][c0 + j];
                a0[j] += w0 * x0.x + w1 * x0.y + w2 * x0.z + w3 * x0.w;
                a1[j] += w0 * x1.x + w1 * x1.y + w2 * x1.z + w3 * x1.w;
            }
        }
        if (row0 < N_NODESC) {
            #pragma unroll
            for (int j = 0; j < 5; j++) out[(size_t)row0 * NCLASS + c0 + j] = a0[j] + b2f[c0 + j];
        }
        if (row1 < N_NODESC) {
            #pragma unroll
            for (int j = 0; j < 5; j++) out[(size_t)row1 * NCLASS + c0 + j] = a1[j] + b2f[c0 + j];
        }
    }
}

extern "C" void kernel_launch(void* const* d_in, const int* in_sizes, int n_in,
                              void* d_out, int out_size, void* d_ws, size_t ws_size,
                              hipStream_t stream) {
    const float* h    = (const float*)d_in[0];
    const int*   src  = (const int*)d_in[1];
    const int*   dst  = (const int*)d_in[2];
    const float* bn_g = (const float*)d_in[3];
    const float* bn_b = (const float*)d_in[4];
    const float* W1   = (const float*)d_in[5];
    const float* b1   = (const float*)d_in[6];
    const float* g2   = (const float*)d_in[7];
    const float* be2  = (const float*)d_in[8];
    const float* W2   = (const float*)d_in[9];
    const float* b2   = (const float*)d_in[10];
    float* out = (float*)d_out;

    // workspace layout (floats; ~56 MB total)
    float* ws      = (float*)d_ws;
    float* nrm     = ws;                                   // 50000
    int*   deg     = (int*)(ws + N_NODESC);                // 50000
    unsigned int* counter = (unsigned int*)(deg + N_NODESC); // pad 64 (zeroed with deg)
    int*   cursor  = (int*)(counter + 64);                 // 50000
    int*   rowptr  = cursor + N_NODESC;                    // pad 50016
    int*   bsums   = rowptr + 50016;                       // 256
    int*   boff    = bsums + 256;                          // 256
    int*   csr     = boff + 256;                           // 600000
    float* partials = (float*)(csr + N_EDGESC);            // 1024*256 = 262144
    float* p2      = partials + 262144;                    // 32*256 = 8192
    float* mu      = p2 + 8192;                            // 128
    float* rstd    = mu + DDIM;                            // 128
    float* W2f     = rstd + DDIM;                          // 5120
    float* b2f     = W2f + DDIM * NCLASS;                  // pad 64
    unsigned short* W1T = (unsigned short*)(b2f + 64);     // 16384 ushort (8192 f)
    unsigned short* Z   = (unsigned short*)((float*)W1T + 8192);   // 6.4M ushort (3.2M f)
    unsigned short* Xb  = (unsigned short*)((float*)Z + 3200000);  // 6.4M ushort (3.2M f)
    float* X       = (float*)((float*)Xb + 3200000);       // 6.4M floats

    (void)in_sizes; (void)n_in; (void)out_size; (void)ws_size;

    // zero deg + counter in one memset
    hipMemsetAsync(deg, 0, (N_NODESC + 64) * sizeof(int), stream);
    deg_kernel<<<(N_EDGESC + 255) / 256, 256, 0, stream>>>(dst, deg);
    scan1_kernel<<<STAT_BLOCKS, 256, 0, stream>>>(deg, rowptr, bsums);
    scan2_kernel<<<1, 256, 0, stream>>>(bsums, boff);
    scan3_kernel<<<STAT_BLOCKS, 256, 0, stream>>>(rowptr, boff, deg, cursor, nrm);
    fill_kernel<<<(N_EDGESC + 255) / 256, 256, 0, stream>>>(src, dst, cursor, csr);
    sortrows_kernel<<<SORT_BLOCKS, 128, 0, stream>>>(rowptr, csr);

    // layer 0: Z = bf16(nrm*h) (+ W1T prep in extra blocks); Xb = bf16(nrm * S(Z)), stats fused
    act0_kernel<<<ACT_BLOCKS + W1P_BLOCKS, 256, 0, stream>>>(h, nrm, Z, W1, W1T);
    gather_kernel<<<GATHER_BLOCKS, 512, 0, stream>>>(Z, nrm, rowptr, csr, Xb, partials);
    redfuse_kernel<false><<<32, 256, 0, stream>>>(partials, GATHER_BLOCKS, p2, counter, mu, rstd,
                                                  nullptr, nullptr, nullptr, nullptr, nullptr, nullptr);
    // layers 1..3: Z = bf16(nrm*relu(BN(Xb))); Xb = bf16(nrm * S(Z))
    for (int l = 1; l < 4; l++) {
        act_bf16_kernel<true><<<ACT_BLOCKS, 256, 0, stream>>>(Xb, nrm, mu, rstd, bn_g, bn_b, Z);
        gather_kernel<<<GATHER_BLOCKS, 512, 0, stream>>>(Z, nrm, rowptr, csr, Xb, partials);
        redfuse_kernel<false><<<32, 256, 0, stream>>>(partials, GATHER_BLOCKS, p2, counter, mu, rstd,
                                                      nullptr, nullptr, nullptr, nullptr, nullptr, nullptr);
    }
    // epilogue: Z = bf16(relu(BN(Xb))); X = Z @ W1 + b1 (MFMA, stats fused);
    // final reduce also folds BN2 into W2f/b2f; out = X @ W2f + b2f
    act_bf16_kernel<false><<<ACT_BLOCKS, 256, 0, stream>>>(Xb, nullptr, mu, rstd, bn_g, bn_b, Z);
    linear1_mfma<<<L1_BLOCKS, 256, 0, stream>>>(Z, W1T, b1, X, partials);
    redfuse_kernel<true><<<32, 256, 0, stream>>>(partials, L1_BLOCKS, p2, counter, mu, rstd,
                                                 W2, b2, g2, be2, W2f, b2f);
    linear2_kernel<<<512, 256, 0, stream>>>(X, W2f, b2f, out);
}

// Round 10
// 369.369 us; speedup vs baseline: 1.0268x; 1.0268x over previous
//
#include <hip/hip_runtime.h>

#define N_NODESC 50000
#define N_EDGESC 600000
#define DDIM 128
#define NCLASS 40
#define BN_EPS 1e-5f
#define STAT_BLOCKS 196     // ceil(50000/256)
#define GATHER_BLOCKS 1024  // x 512 threads (8 waves)
#define L1_BLOCKS 782       // 3128 tiles of 16 rows
#define ACT_BLOCKS 3125     // 50000*16/256
#define W1P_BLOCKS 64       // 16384/256
#define SORT_ROWS 128
#define SORT_CAP 2560
#define SORT_BLOCKS 391

typedef short bhalf8 __attribute__((ext_vector_type(8)));
typedef float f32x4 __attribute__((ext_vector_type(4)));

union ABfrag { bhalf8 v; unsigned short u[8]; uint4 q; };

__device__ inline float bflo(unsigned d) { return __builtin_bit_cast(float, d << 16); }
__device__ inline float bfhi(unsigned d) { return __builtin_bit_cast(float, d & 0xffff0000u); }
__device__ inline unsigned short f2bf(float f) {
    unsigned u = __builtin_bit_cast(unsigned, f);
    u += 0x7fffu + ((u >> 16) & 1u);        // RNE
    return (unsigned short)(u >> 16);
}

// ---------------- degree (int4-vectorized: 4 edges/thread) ----------------
__global__ __launch_bounds__(256) void deg_kernel(const int* __restrict__ dst, int* __restrict__ deg) {
    int e4 = blockIdx.x * 256 + threadIdx.x;   // 150000 quads
    if (e4 < N_EDGESC / 4) {
        int4 d = reinterpret_cast<const int4*>(dst)[e4];
        atomicAdd(&deg[d.x], 1);
        atomicAdd(&deg[d.y], 1);
        atomicAdd(&deg[d.z], 1);
        atomicAdd(&deg[d.w], 1);
    }
}

// ---------------- hierarchical exclusive scan: deg -> rowptr (+ nrm fused) ----------------
__global__ __launch_bounds__(256) void scan1_kernel(const int* __restrict__ deg,
                                                    int* __restrict__ rowptr,
                                                    int* __restrict__ blocksums) {
    __shared__ int sh[256];
    int t = threadIdx.x;
    int i = blockIdx.x * 256 + t;
    int v = (i < N_NODESC) ? deg[i] : 0;
    sh[t] = v;
    __syncthreads();
    #pragma unroll
    for (int off = 1; off < 256; off <<= 1) {
        int tv = (t >= off) ? sh[t - off] : 0;
        __syncthreads();
        sh[t] += tv;
        __syncthreads();
    }
    if (i < N_NODESC) rowptr[i] = sh[t] - v;
    if (t == 255) blocksums[blockIdx.x] = sh[255];
}

__global__ void scan2_kernel(const int* __restrict__ blocksums, int* __restrict__ blockoff) {
    __shared__ int sh[256];
    int t = threadIdx.x;
    int v = (t < STAT_BLOCKS) ? blocksums[t] : 0;
    sh[t] = v;
    __syncthreads();
    #pragma unroll
    for (int off = 1; off < 256; off <<= 1) {
        int tv = (t >= off) ? sh[t - off] : 0;
        __syncthreads();
        sh[t] += tv;
        __syncthreads();
    }
    blockoff[t] = sh[t] - v;
}

__global__ __launch_bounds__(256) void scan3_kernel(int* __restrict__ rowptr,
                                                    const int* __restrict__ blockoff,
                                                    const int* __restrict__ deg,
                                                    int* __restrict__ cursor,
                                                    float* __restrict__ nrm) {
    int i = blockIdx.x * 256 + threadIdx.x;
    if (i < N_NODESC) {
        int r = rowptr[i] + blockoff[blockIdx.x];
        rowptr[i] = r;
        cursor[i] = r;
        nrm[i] = rsqrtf(fmaxf((float)deg[i], 1.0f));
    }
    if (blockIdx.x == 0 && threadIdx.x == 0) rowptr[N_NODESC] = N_EDGESC;
}

// ---------------- CSR fill (int4-vectorized) + deterministic per-row LDS sort ----------------
__global__ __launch_bounds__(256) void fill_kernel(const int* __restrict__ src,
                                                   const int* __restrict__ dst,
                                                   int* __restrict__ cursor,
                                                   int* __restrict__ csr) {
    int e4 = blockIdx.x * 256 + threadIdx.x;
    if (e4 < N_EDGESC / 4) {
        int4 d = reinterpret_cast<const int4*>(dst)[e4];
        int4 s = reinterpret_cast<const int4*>(src)[e4];
        csr[atomicAdd(&cursor[d.x], 1)] = s.x;
        csr[atomicAdd(&cursor[d.y], 1)] = s.y;
        csr[atomicAdd(&cursor[d.z], 1)] = s.z;
        csr[atomicAdd(&cursor[d.w], 1)] = s.w;
    }
}

__global__ __launch_bounds__(128) void sortrows_kernel(const int* __restrict__ rowptr,
                                                       int* __restrict__ csr) {
    __shared__ int buf[SORT_CAP];
    int r0 = blockIdx.x * SORT_ROWS;
    int r1 = r0 + SORT_ROWS; if (r1 > N_NODESC) r1 = N_NODESC;
    int base = rowptr[r0];
    int end  = rowptr[r1];
    int cnt  = end - base;
    if (cnt <= SORT_CAP) {
        for (int j = threadIdx.x; j < cnt; j += 128) buf[j] = csr[base + j];
        __syncthreads();
        int i = r0 + threadIdx.x;
        if (i < r1) {
            int b = rowptr[i] - base, e = rowptr[i + 1] - base;
            for (int j = b + 1; j < e; j++) {
                int v = buf[j];
                int k = j - 1;
                while (k >= b && buf[k] > v) { buf[k + 1] = buf[k]; k--; }
                buf[k + 1] = v;
            }
        }
        __syncthreads();
        for (int j = threadIdx.x; j < cnt; j += 128) csr[base + j] = buf[j];
    } else {
        int i = r0 + threadIdx.x;
        if (i < r1) {
            int b = rowptr[i], e = rowptr[i + 1];
            for (int j = b + 1; j < e; j++) {
                int v = csr[j];
                int k = j - 1;
                while (k >= b && csr[k] > v) { csr[k + 1] = csr[k]; k--; }
                csr[k + 1] = v;
            }
        }
    }
}

// ---------------- layer-0 act (fp32 in): Z = bf16(nrm*h); extra blocks do W1 -> bf16 [n][k] ----------------
__global__ __launch_bounds__(256) void act0_kernel(const float* __restrict__ in,
                                                   const float* __restrict__ nrm,
                                                   unsigned short* __restrict__ Z,
                                                   const float* __restrict__ W1,
                                                   unsigned short* __restrict__ W1T) {
    if (blockIdx.x >= ACT_BLOCKS) {
        int idx = (blockIdx.x - ACT_BLOCKS) * 256 + threadIdx.x;
        if (idx < DDIM * DDIM) {
            int k = idx >> 7, n = idx & 127;
            W1T[n * DDIM + k] = f2bf(W1[idx]);
        }
        return;
    }
    int t = blockIdx.x * 256 + threadIdx.x;
    int i = t >> 4;
    int c = (t & 15) * 8;
    if (i >= N_NODESC) return;
    const float* rp = in + (size_t)i * DDIM + c;
    float4 v0 = *reinterpret_cast<const float4*>(rp);
    float4 v1 = *reinterpret_cast<const float4*>(rp + 4);
    float ni = nrm[i];
    float a[8] = {v0.x*ni, v0.y*ni, v0.z*ni, v0.w*ni, v1.x*ni, v1.y*ni, v1.z*ni, v1.w*ni};
    uint4 p;
    p.x = (unsigned)f2bf(a[0]) | ((unsigned)f2bf(a[1]) << 16);
    p.y = (unsigned)f2bf(a[2]) | ((unsigned)f2bf(a[3]) << 16);
    p.z = (unsigned)f2bf(a[4]) | ((unsigned)f2bf(a[5]) << 16);
    p.w = (unsigned)f2bf(a[6]) | ((unsigned)f2bf(a[7]) << 16);
    *reinterpret_cast<uint4*>(Z + (size_t)i * DDIM + c) = p;
}

// ---------------- activation prepass (bf16 in): Z = bf16( nrm * relu(x*sc+sh) ) ----------------
__global__ __launch_bounds__(256) void act_bf16_kernel(const unsigned short* __restrict__ in,
                                                       const float* __restrict__ nrm,
                                                       const float* __restrict__ mu,
                                                       const float* __restrict__ rstd,
                                                       const float* __restrict__ gamma,
                                                       const float* __restrict__ beta,
                                                       unsigned short* __restrict__ Z) {
    int t = blockIdx.x * 256 + threadIdx.x;
    int i = t >> 4;
    int c = (t & 15) * 8;
    if (i >= N_NODESC) return;
    uint4 d = *reinterpret_cast<const uint4*>(in + (size_t)i * DDIM + c);
    float a[8] = {bflo(d.x), bfhi(d.x), bflo(d.y), bfhi(d.y),
                  bflo(d.z), bfhi(d.z), bflo(d.w), bfhi(d.w)};
    float4 m0 = *reinterpret_cast<const float4*>(mu + c);
    float4 m1 = *reinterpret_cast<const float4*>(mu + c + 4);
    float4 r0 = *reinterpret_cast<const float4*>(rstd + c);
    float4 r1 = *reinterpret_cast<const float4*>(rstd + c + 4);
    float4 g0 = *reinterpret_cast<const float4*>(gamma + c);
    float4 g1 = *reinterpret_cast<const float4*>(gamma + c + 4);
    float4 b0 = *reinterpret_cast<const float4*>(beta + c);
    float4 b1 = *reinterpret_cast<const float4*>(beta + c + 4);
    float sc[8] = {r0.x*g0.x, r0.y*g0.y, r0.z*g0.z, r0.w*g0.w,
                   r1.x*g1.x, r1.y*g1.y, r1.z*g1.z, r1.w*g1.w};
    float sh[8] = {b0.x-m0.x*sc[0], b0.y-m0.y*sc[1], b0.z-m0.z*sc[2], b0.w-m0.w*sc[3],
                   b1.x-m1.x*sc[4], b1.y-m1.y*sc[5], b1.z-m1.z*sc[6], b1.w-m1.w*sc[7]};
    float ni = nrm[i];
    #pragma unroll
    for (int k = 0; k < 8; k++) a[k] = fmaxf(a[k] * sc[k] + sh[k], 0.f) * ni;
    uint4 p;
    p.x = (unsigned)f2bf(a[0]) | ((unsigned)f2bf(a[1]) << 16);
    p.y = (unsigned)f2bf(a[2]) | ((unsigned)f2bf(a[3]) << 16);
    p.z = (unsigned)f2bf(a[4]) | ((unsigned)f2bf(a[5]) << 16);
    p.w = (unsigned)f2bf(a[6]) | ((unsigned)f2bf(a[7]) << 16);
    *reinterpret_cast<uint4*>(Z + (size_t)i * DDIM + c) = p;
}

// ---------------- gather: Xb[i] = bf16(nrm[i] * sum Z[s]); fused BN stats (pre-round fp32) ----------------
// 512 threads = 8 waves; wave: 4 edge slots x 16 col-lanes (8 cols each); 2-deep row prefetch
__global__ __launch_bounds__(512) void gather_kernel(const unsigned short* __restrict__ Z,
                                                     const float* __restrict__ nrm,
                                                     const int* __restrict__ rowptr,
                                                     const int* __restrict__ csr,
                                                     unsigned short* __restrict__ Xb,
                                                     float* __restrict__ partials) {
    __shared__ float red[8][256];
    int lane = threadIdx.x & 63;
    int wave = threadIdx.x >> 6;   // 0..7
    int slot = lane >> 4;          // 0..3
    int c    = lane & 15;          // col group: cols [8c, 8c+8)
    float ssum[8] = {0.f,0.f,0.f,0.f,0.f,0.f,0.f,0.f};
    float sqr[8]  = {0.f,0.f,0.f,0.f,0.f,0.f,0.f,0.f};
    for (int i = blockIdx.x * 8 + wave; i < N_NODESC; i += GATHER_BLOCKS * 8) {
        int b = rowptr[i], e = rowptr[i + 1];
        float a[8] = {0.f,0.f,0.f,0.f,0.f,0.f,0.f,0.f};
        int j = b + slot;
        bool v0 = j < e, v1 = j + 4 < e, v2 = j + 8 < e;
        uint4 r0 = make_uint4(0,0,0,0), r1 = r0, r2 = r0;
        if (v0) r0 = reinterpret_cast<const uint4*>(Z + (size_t)csr[j]     * DDIM)[c];
        if (v1) r1 = reinterpret_cast<const uint4*>(Z + (size_t)csr[j + 4] * DDIM)[c];
        if (v2) r2 = reinterpret_cast<const uint4*>(Z + (size_t)csr[j + 8] * DDIM)[c];
        int jn = j + 12;
        while (v0) {
            a[0] += bflo(r0.x); a[1] += bfhi(r0.x);
            a[2] += bflo(r0.y); a[3] += bfhi(r0.y);
            a[4] += bflo(r0.z); a[5] += bfhi(r0.z);
            a[6] += bflo(r0.w); a[7] += bfhi(r0.w);
            r0 = r1; v0 = v1;
            r1 = r2; v1 = v2;
            v2 = jn < e;
            if (v2) r2 = reinterpret_cast<const uint4*>(Z + (size_t)csr[jn] * DDIM)[c];
            jn += 4;
        }
        #pragma unroll
        for (int t = 0; t < 8; t++) {
            a[t] += __shfl_xor(a[t], 16);
            a[t] += __shfl_xor(a[t], 32);
        }
        if (slot == 0) {
            float ni = nrm[i];
            #pragma unroll
            for (int t = 0; t < 8; t++) {
                a[t] *= ni;
                ssum[t] += a[t];
                sqr[t]  += a[t] * a[t];
            }
            uint4 p;
            p.x = (unsigned)f2bf(a[0]) | ((unsigned)f2bf(a[1]) << 16);
            p.y = (unsigned)f2bf(a[2]) | ((unsigned)f2bf(a[3]) << 16);
            p.z = (unsigned)f2bf(a[4]) | ((unsigned)f2bf(a[5]) << 16);
            p.w = (unsigned)f2bf(a[6]) | ((unsigned)f2bf(a[7]) << 16);
            reinterpret_cast<uint4*>(Xb + (size_t)i * DDIM)[c] = p;
        }
    }
    if (slot == 0) {
        #pragma unroll
        for (int t = 0; t < 8; t++) {
            red[wave][c * 8 + t]       = ssum[t];
            red[wave][128 + c * 8 + t] = sqr[t];
        }
    }
    __syncthreads();
    int tid = threadIdx.x;
    if (tid < 256) {
        float s = 0.f;
        #pragma unroll
        for (int w = 0; w < 8; w++) s += red[w][tid];
        partials[(size_t)blockIdx.x * 256 + tid] = s;
    }
}

// ---------------- fused deterministic stats reduce: 32 blocks; last block finishes in fp64 ----------------
// FOLD=true additionally folds BN2 into W2/b2 in the last block.
template <bool FOLD>
__global__ __launch_bounds__(256) void redfuse_kernel(const float* __restrict__ partials, int nrows,
                                                      float* __restrict__ p2,
                                                      unsigned int* __restrict__ counter,
                                                      float* __restrict__ mu, float* __restrict__ rstd,
                                                      const float* __restrict__ W2, const float* __restrict__ b2,
                                                      const float* __restrict__ g2, const float* __restrict__ be2,
                                                      float* __restrict__ W2f, float* __restrict__ b2f) {
    int col = threadIdx.x;
    float s = 0.f;
    for (int r = blockIdx.x; r < nrows; r += 32) s += partials[(size_t)r * 256 + col];
    p2[(size_t)blockIdx.x * 256 + col] = s;
    __threadfence();
    __shared__ unsigned int lastFlag;
    if (col == 0) lastFlag = (atomicAdd(counter, 1u) == 31u) ? 1u : 0u;
    __syncthreads();
    if (!lastFlag) return;
    if (col == 0) *counter = 0u;          // self-reset for the next use
    __threadfence();                      // acquire: see all p2 writes
    int c = col & 127;
    int isq = col >> 7;
    double acc = 0.0;
    for (int r = 0; r < 32; r++) acc += (double)p2[(size_t)r * 256 + isq * 128 + c];
    __shared__ double shd[256];
    __shared__ float sfold[128], tfold[128];
    __shared__ float f4[4][64];
    shd[col] = acc;
    __syncthreads();
    if (col < 128) {
        double m = shd[col] / (double)N_NODESC;
        double v = shd[col + 128] / (double)N_NODESC - m * m;
        if (v < 0.0) v = 0.0;
        float rs = rsqrtf((float)v + BN_EPS);
        mu[col]   = (float)m;
        rstd[col] = rs;
        if (FOLD) {
            float sc = rs * g2[col];
            sfold[col] = sc;
            tfold[col] = be2[col] - (float)m * sc;
        }
    }
    if (FOLD) {
        __syncthreads();
        for (int idx = col; idx < DDIM * NCLASS; idx += 256) {
            W2f[idx] = W2[idx] * sfold[idx / NCLASS];
        }
        int c2 = col & 63, sl2 = col >> 6;
        float accf = 0.f;
        if (c2 < NCLASS) {
            for (int k = sl2 * 32; k < sl2 * 32 + 32; k++) accf += tfold[k] * W2[k * NCLASS + c2];
        }
        f4[sl2][c2] = accf;
        __syncthreads();
        if (col < NCLASS) {
            b2f[col] = b2[col] + f4[0][col] + f4[1][col] + f4[2][col] + f4[3][col];
        }
    }
}

// ---------------- GEMM1 (MFMA): X = relu(BN(Xb)) @ W1 + b1 (BN+ReLU on A-frags in regs), fused BN2 stats ----------------
__global__ __launch_bounds__(256) void linear1_mfma(const unsigned short* __restrict__ Xb,
                                                    const unsigned short* __restrict__ W1T,
                                                    const float* __restrict__ b1,
                                                    const float* __restrict__ mu,
                                                    const float* __restrict__ rstd,
                                                    const float* __restrict__ gamma,
                                                    const float* __restrict__ beta,
                                                    float* __restrict__ X,
                                                    float* __restrict__ partials) {
    __shared__ uint4 wlds[2048];               // 32 KB: W1T bf16 [n][k], XOR-swizzled
    __shared__ float scs[DDIM], shs[DDIM], bias[DDIM];
    __shared__ float red[4][256];
    int tid = threadIdx.x;
    for (int i = tid; i < 2048; i += 256) {
        uint4 v = reinterpret_cast<const uint4*>(W1T)[i];
        int o = i << 4;
        int n = o >> 8;
        int sw = (o & 255) ^ ((n & 7) << 4);
        wlds[(n << 4) | (sw >> 4)] = v;
    }
    if (tid < DDIM) {
        float a = rstd[tid] * gamma[tid];
        scs[tid] = a;
        shs[tid] = beta[tid] - mu[tid] * a;
        bias[tid] = b1[tid];
    }
    __syncthreads();
    int wave = tid >> 6, lane = tid & 63;
    int l15 = lane & 15, l4 = lane >> 4;
    int tile = blockIdx.x * 4 + wave;          // < 3128
    int row0 = tile * 16;
    int arow = row0 + l15; if (arow >= N_NODESC) arow = N_NODESC - 1;
    const uint4* aptr = reinterpret_cast<const uint4*>(Xb + (size_t)arow * DDIM);
    f32x4 acc[8];
    #pragma unroll
    for (int cf = 0; cf < 8; cf++) acc[cf] = (f32x4){0.f, 0.f, 0.f, 0.f};
    #pragma unroll
    for (int ks = 0; ks < 4; ks++) {
        uint4 ad = aptr[ks * 4 + l4];
        int kb = ks * 32 + l4 * 8;
        ABfrag a;
        float f;
        f = bflo(ad.x); a.u[0] = f2bf(fmaxf(f * scs[kb + 0] + shs[kb + 0], 0.f));
        f = bfhi(ad.x); a.u[1] = f2bf(fmaxf(f * scs[kb + 1] + shs[kb + 1], 0.f));
        f = bflo(ad.y); a.u[2] = f2bf(fmaxf(f * scs[kb + 2] + shs[kb + 2], 0.f));
        f = bfhi(ad.y); a.u[3] = f2bf(fmaxf(f * scs[kb + 3] + shs[kb + 3], 0.f));
        f = bflo(ad.z); a.u[4] = f2bf(fmaxf(f * scs[kb + 4] + shs[kb + 4], 0.f));
        f = bfhi(ad.z); a.u[5] = f2bf(fmaxf(f * scs[kb + 5] + shs[kb + 5], 0.f));
        f = bflo(ad.w); a.u[6] = f2bf(fmaxf(f * scs[kb + 6] + shs[kb + 6], 0.f));
        f = bfhi(ad.w); a.u[7] = f2bf(fmaxf(f * scs[kb + 7] + shs[kb + 7], 0.f));
        int koff = ks * 64 + l4 * 16;
        #pragma unroll
        for (int cf = 0; cf < 8; cf++) {
            int n = cf * 16 + l15;
            ABfrag b;
            b.q = wlds[(n << 4) | ((koff ^ ((n & 7) << 4)) >> 4)];
            acc[cf] = __builtin_amdgcn_mfma_f32_16x16x32_bf16(a.v, b.v, acc[cf], 0, 0, 0);
        }
    }
    float cs[8], cq[8];
    #pragma unroll
    for (int cf = 0; cf < 8; cf++) {
        int col = cf * 16 + l15;
        float bb = bias[col];
        float sl_ = 0.f, ql_ = 0.f;
        #pragma unroll
        for (int r = 0; r < 4; r++) {
            int row = row0 + l4 * 4 + r;
            float x = acc[cf][r] + bb;
            if (row < N_NODESC) {
                X[(size_t)row * DDIM + col] = x;
                sl_ += x;
                ql_ += x * x;
            }
        }
        sl_ += __shfl_xor(sl_, 16); sl_ += __shfl_xor(sl_, 32);
        ql_ += __shfl_xor(ql_, 16); ql_ += __shfl_xor(ql_, 32);
        cs[cf] = sl_; cq[cf] = ql_;
    }
    if (l4 == 0) {
        #pragma unroll
        for (int cf = 0; cf < 8; cf++) {
            red[wave][cf * 16 + l15]       = cs[cf];
            red[wave][128 + cf * 16 + l15] = cq[cf];
        }
    }
    __syncthreads();
    if (tid < 256) {
        partials[(size_t)blockIdx.x * 256 + tid] = red[0][tid] + red[1][tid] + red[2][tid] + red[3][tid];
    }
}

// ---------------- GEMM2: out = X @ W2f + b2f ----------------
#define L2_TILE 64
__global__ __launch_bounds__(256) void linear2_kernel(const float* __restrict__ X,
                                                      const float* __restrict__ W2f,
                                                      const float* __restrict__ b2f,
                                                      float* __restrict__ out) {
    __shared__ float Ws[DDIM][NCLASS];  // 20 KB
    for (int idx = threadIdx.x; idx < DDIM * NCLASS; idx += 256) {
        (&Ws[0][0])[idx] = W2f[idx];
    }
    __syncthreads();
    int cg = threadIdx.x & 7;
    int rp = threadIdx.x >> 3;
    int c0 = cg * 5;
    for (int base = blockIdx.x * L2_TILE; base < N_NODESC; base += gridDim.x * L2_TILE) {
        int row0 = base + rp * 2;
        int row1 = row0 + 1;
        int r0c = row0 < N_NODESC ? row0 : (N_NODESC - 1);
        int r1c = row1 < N_NODESC ? row1 : (N_NODESC - 1);
        const float* r0p = X + (size_t)r0c * DDIM;
        const float* r1p = X + (size_t)r1c * DDIM;
        float a0[5] = {0.f, 0.f, 0.f, 0.f, 0.f};
        float a1[5] = {0.f, 0.f, 0.f, 0.f, 0.f};
        #pragma unroll 4
        for (int k4 = 0; k4 < DDIM; k4 += 4) {
            float4 x0 = *reinterpret_cast<const float4*>(r0p + k4);
            float4 x1 = *reinterpret_cast<const float4*>(r1p + k4);
            #pragma unroll
            for (int j = 0; j < 5; j++) {
                float w0 = Ws[k4 + 0][c0 + j];
                float w1 = Ws[k4 + 1][c0 + j];
                float w2 = Ws[k4 + 2][c0 + j];
                float w3 = Ws[k4 + 3][c0 + j];
                a0[j] += w0 * x0.x + w1 * x0.y + w2 * x0.z + w3 * x0.w;
                a1[j] += w0 * x1.x + w1 * x1.y + w2 * x1.z + w3 * x1.w;
            }
        }
        if (row0 < N_NODESC) {
            #pragma unroll
            for (int j = 0; j < 5; j++) out[(size_t)row0 * NCLASS + c0 + j] = a0[j] + b2f[c0 + j];
        }
        if (row1 < N_NODESC) {
            #pragma unroll
            for (int j = 0; j < 5; j++) out[(size_t)row1 * NCLASS + c0 + j] = a1[j] + b2f[c0 + j];
        }
    }
}

extern "C" void kernel_launch(void* const* d_in, const int* in_sizes, int n_in,
                              void* d_out, int out_size, void* d_ws, size_t ws_size,
                              hipStream_t stream) {
    const float* h    = (const float*)d_in[0];
    const int*   src  = (const int*)d_in[1];
    const int*   dst  = (const int*)d_in[2];
    const float* bn_g = (const float*)d_in[3];
    const float* bn_b = (const float*)d_in[4];
    const float* W1   = (const float*)d_in[5];
    const float* b1   = (const float*)d_in[6];
    const float* g2   = (const float*)d_in[7];
    const float* be2  = (const float*)d_in[8];
    const float* W2   = (const float*)d_in[9];
    const float* b2   = (const float*)d_in[10];
    float* out = (float*)d_out;

    // workspace layout (floats; ~56 MB total)
    float* ws      = (float*)d_ws;
    float* nrm     = ws;                                   // 50000
    int*   deg     = (int*)(ws + N_NODESC);                // 50000
    unsigned int* counter = (unsigned int*)(deg + N_NODESC); // pad 64 (zeroed with deg)
    int*   cursor  = (int*)(counter + 64);                 // 50000
    int*   rowptr  = cursor + N_NODESC;                    // pad 50016
    int*   bsums   = rowptr + 50016;                       // 256
    int*   boff    = bsums + 256;                          // 256
    int*   csr     = boff + 256;                           // 600000
    float* partials = (float*)(csr + N_EDGESC);            // 1024*256 = 262144
    float* p2      = partials + 262144;                    // 32*256 = 8192
    float* mu      = p2 + 8192;                            // 128
    float* rstd    = mu + DDIM;                            // 128
    float* W2f     = rstd + DDIM;                          // 5120
    float* b2f     = W2f + DDIM * NCLASS;                  // pad 64
    unsigned short* W1T = (unsigned short*)(b2f + 64);     // 16384 ushort (8192 f)
    unsigned short* Z   = (unsigned short*)((float*)W1T + 8192);   // 6.4M ushort (3.2M f)
    unsigned short* Xb  = (unsigned short*)((float*)Z + 3200000);  // 6.4M ushort (3.2M f)
    float* X       = (float*)((float*)Xb + 3200000);       // 6.4M floats

    (void)in_sizes; (void)n_in; (void)out_size; (void)ws_size;

    // zero deg + counter in one memset
    hipMemsetAsync(deg, 0, (N_NODESC + 64) * sizeof(int), stream);
    deg_kernel<<<(N_EDGESC / 4 + 255) / 256, 256, 0, stream>>>(dst, deg);
    scan1_kernel<<<STAT_BLOCKS, 256, 0, stream>>>(deg, rowptr, bsums);
    scan2_kernel<<<1, 256, 0, stream>>>(bsums, boff);
    scan3_kernel<<<STAT_BLOCKS, 256, 0, stream>>>(rowptr, boff, deg, cursor, nrm);
    fill_kernel<<<(N_EDGESC / 4 + 255) / 256, 256, 0, stream>>>(src, dst, cursor, csr);
    sortrows_kernel<<<SORT_BLOCKS, 128, 0, stream>>>(rowptr, csr);

    // layer 0: Z = bf16(nrm*h) (+ W1T prep in extra blocks); Xb = bf16(nrm * S(Z)), stats fused
    act0_kernel<<<ACT_BLOCKS + W1P_BLOCKS, 256, 0, stream>>>(h, nrm, Z, W1, W1T);
    gather_kernel<<<GATHER_BLOCKS, 512, 0, stream>>>(Z, nrm, rowptr, csr, Xb, partials);
    redfuse_kernel<false><<<32, 256, 0, stream>>>(partials, GATHER_BLOCKS, p2, counter, mu, rstd,
                                                  nullptr, nullptr, nullptr, nullptr, nullptr, nullptr);
    // layers 1..3: Z = bf16(nrm*relu(BN(Xb))); Xb = bf16(nrm * S(Z))
    for (int l = 1; l < 4; l++) {
        act_bf16_kernel<<<ACT_BLOCKS, 256, 0, stream>>>(Xb, nrm, mu, rstd, bn_g, bn_b, Z);
        gather_kernel<<<GATHER_BLOCKS, 512, 0, stream>>>(Z, nrm, rowptr, csr, Xb, partials);
        redfuse_kernel<false><<<32, 256, 0, stream>>>(partials, GATHER_BLOCKS, p2, counter, mu, rstd,
                                                      nullptr, nullptr, nullptr, nullptr, nullptr, nullptr);
    }
    // epilogue: X = relu(BN(Xb)) @ W1 + b1 (BN fused into MFMA A-frags, stats fused);
    // final reduce also folds BN2 into W2f/b2f; out = X @ W2f + b2f
    linear1_mfma<<<L1_BLOCKS, 256, 0, stream>>>(Xb, W1T, b1, mu, rstd, bn_g, bn_b, X, partials);
    redfuse_kernel<true><<<32, 256, 0, stream>>>(partials, L1_BLOCKS, p2, counter, mu, rstd,
                                                 W2, b2, g2, be2, W2f, b2f);
    linear2_kernel<<<512, 256, 0, stream>>>(X, W2f, b2f, out);
}